// Round 2
// baseline (365.237 us; speedup 1.0000x reference)
//
#include <hip/hip_runtime.h>
#include <math.h>

// EdgeFeaturizer: per-row top-12 smallest of 8192x8192 fp32 + 50-bin RBF.
// d_out (float32): [8192*12*2] edge_index encoded as floats, then
// [8192*12*50] features.
//
// R6 (carried): unordered LDS atomic append (rank-select is order-
// independent), LDS ~6.6 KiB/block, __launch_bounds__(256,8) -> full
// 32-wave/CU residency. Measured null vs R5 -> kernel is not
// occupancy/VALU-bound; window is HBM-traffic-bound.
//
// R7 EXPERIMENT: phase-1 loads nt -> NORMAL (allocating). dm is exactly
// 256 MiB = Infinity Cache size. nt loads guarantee dm re-reads HBM every
// replay; allocating loads allow L3 residency across replays. R5's claim
// (allocating reads force dirty-poison writebacks) is contradicted by the
// fill dispatches' own counters (WRITE_SIZE = 1 GiB drained inside the
// fill's 162 us window). 3-way prediction: L3-resident -> ~210-260 us;
// R5 mechanism real -> ~500 us (revert); fill thrashes L3 -> unchanged
// (-> mandatory-bytes roofline). Output stores stay nt (never re-read).
//
// Key=(float_bits<<32)|idx == top_k's (dist asc, idx asc) order.
// Exact per-wave fallback guarantees correctness for any input.

#define N_ATOMS 8192
#define K 12
#define NBINS 50
#define CAP 192          // total candidates/row: Binom(8192,0.01) mean 82
#define WAVES 4
#define BLOCK (WAVES * 64)
#define MAX_RADIUS 8.0f
#define CAND_T 0.01f

typedef float f4 __attribute__((ext_vector_type(4)));

__global__ __launch_bounds__(BLOCK, 8) void edge_kernel(const float* __restrict__ dm,
                                                        float* __restrict__ out) {
    const int wave = threadIdx.x >> 6;
    const int lane = threadIdx.x & 63;
    const int row = blockIdx.x * WAVES + wave;
    const float* rowp = dm + (size_t)row * N_ATOMS;
    const f4* row4 = (const f4*)rowp;

    __shared__ unsigned long long s_keys[WAVES][CAP];  // 6 KiB
    __shared__ int s_cnt[WAVES];
    __shared__ int s_selidx[WAVES][K];
    __shared__ float s_seldist[WAVES][K];

    // Same-wave DS ops complete in order: lane0's init is visible to this
    // wave's later atomics without a block barrier.
    if (lane == 0) s_cnt[wave] = 0;

    // ---- phase 1: streaming scan (ALLOCATING loads), unordered append ----
    #pragma unroll
    for (int i = 0; i < 8; ++i) {
        f4 v[4];
        #pragma unroll
        for (int j = 0; j < 4; ++j)
            v[j] = row4[lane + (i * 4 + j) * 64];
        #pragma unroll
        for (int j = 0; j < 4; ++j) {
            int bidx = (lane + (i * 4 + j) * 64) * 4;
            #pragma unroll
            for (int c = 0; c < 4; ++c) {
                float d = v[j][c];
                if (d < CAND_T) {
                    int pos = atomicAdd(&s_cnt[wave], 1);
                    if (pos < CAP)
                        s_keys[wave][pos] =
                            ((unsigned long long)__float_as_uint(d) << 32) |
                            (unsigned int)(bidx + c);
                }
            }
        }
    }
    __syncthreads();  // LDS write->read visibility (and keeps waves phased)

    const int total = s_cnt[wave];

    if (total >= K && total <= CAP) {
        // ---- rank select: rank = #keys strictly smaller (keys unique) ----
        for (int j = lane; j < total; j += 64) {
            unsigned long long kj = s_keys[wave][j];
            int rank = 0;
            for (int m2 = 0; m2 < total; ++m2)       // broadcast reads
                rank += (s_keys[wave][m2] < kj) ? 1 : 0;
            if (rank < K) {
                s_selidx[wave][rank] = (int)(kj & 0xFFFFFFFFull);
                s_seldist[wave][rank] =
                    __uint_as_float((unsigned int)(kj >> 32));
            }
        }
    } else {
        // ---- exact per-wave fallback (never taken on this input) ----
        unsigned long long last = 0ull;
        for (int r = 0; r < K; ++r) {
            unsigned long long best = ~0ull;
            for (int i = 0; i < 32; ++i) {
                int v4 = lane + i * 64;
                f4 v = row4[v4];
                int bidx = v4 * 4;
                #pragma unroll
                for (int c = 0; c < 4; ++c) {
                    float d = v[c];
                    float md = (d <= MAX_RADIUS) ? d
                                                 : __uint_as_float(0x7F800000u);
                    unsigned long long key =
                        ((unsigned long long)__float_as_uint(md) << 32) |
                        (unsigned int)(bidx + c);
                    if (((r == 0) || (key > last)) && key < best) best = key;
                }
            }
            #pragma unroll
            for (int off = 32; off > 0; off >>= 1) {
                unsigned long long other = __shfl_xor(best, off, 64);
                if (other < best) best = other;
            }
            if (lane == 0) {
                int idx = (int)(best & 0xFFFFFFFFull);
                s_selidx[wave][r] = idx;
                s_seldist[wave][r] = rowp[idx];  // original dm value
            }
            last = best;
        }
    }

    // ---- outputs (non-temporal: never re-read). Same-wave DS ordering
    // makes selidx/seldist visible without another barrier. ----
    float* out_ei = out;
    float* out_ef = out + (size_t)N_ATOMS * K * 2;
    if (lane < 2 * K) {
        int r = lane >> 1, comp = lane & 1;
        __builtin_nontemporal_store(
            comp ? (float)s_selidx[wave][r] : (float)row,
            &out_ei[((size_t)row * K + r) * 2 + comp]);
    }
    for (int t = lane; t < K * NBINS; t += 64) {
        int r = t / NBINS, b = t - r * NBINS;
        float d = s_seldist[wave][r];
        float z = (d - (float)b * (1.0f / 49.0f)) * 5.0f;
        __builtin_nontemporal_store(__expf(-0.5f * z * z),
                                    &out_ef[(size_t)row * K * NBINS + t]);
    }
}

extern "C" void kernel_launch(void* const* d_in, const int* in_sizes, int n_in,
                              void* d_out, int out_size, void* d_ws, size_t ws_size,
                              hipStream_t stream) {
    const float* dm = (const float*)d_in[0];
    float* out = (float*)d_out;
    edge_kernel<<<N_ATOMS / WAVES, BLOCK, 0, stream>>>(dm, out);
}

// Round 3
// 340.550 us; speedup vs baseline: 1.0725x; 1.0725x over previous
//
#include <hip/hip_runtime.h>
#include <math.h>

// EdgeFeaturizer: per-row top-12 smallest of 8192x8192 fp32 + 50-bin RBF.
// d_out (float32): [8192*12*2] edge_index encoded as floats, then
// [8192*12*50] features.
//
// R7 post-mortem: allocating loads +23 us vs nt (dirty-poison evictions;
// L3 can never hold dm across replays because the 1 GiB fill re-dirties
// it). nt loads REVERTED IN (best known: 342.2 us).
//
// R8 EXPERIMENT: block-per-row read pattern. Previous structure had all
// 8192 waves co-resident each streaming a private 32 KB row -> 1 KB
// requests scattered over the whole 256 MB at 32 KB stride (8192
// concurrent DRAM page streams). The 6.3-6.6 TB/s reference streams
// (copy bench, poison fill) all have compact sliding-window footprints.
// Here: one 512-thread block per row; a row is consumed in 4 block-wide
// instruction groups; ~1024 resident blocks dispatched in order give a
// ~32 MB contiguous sliding window. Predictions: pattern-limited ->
// <=315 us; already-saturated -> null (declare roofline next round);
// pipeline too coarse -> ~360 (revert).
//
// Key=(float_bits<<32)|idx == top_k's (dist asc, idx asc) order.
// Exact wave-0 fallback guarantees correctness for any input.

#define N_ATOMS 8192
#define K 12
#define NBINS 50
#define CAP 192          // total candidates/row: Binom(8192,0.01) mean 82
#define BLOCK 512
#define MAX_RADIUS 8.0f
#define CAND_T 0.01f

typedef float f4 __attribute__((ext_vector_type(4)));

__global__ __launch_bounds__(BLOCK, 8) void edge_kernel(const float* __restrict__ dm,
                                                        float* __restrict__ out) {
    const int tid = threadIdx.x;
    const int row = blockIdx.x;
    const float* rowp = dm + (size_t)row * N_ATOMS;
    const f4* row4 = (const f4*)rowp;

    __shared__ unsigned long long s_keys[CAP];  // 1.5 KiB
    __shared__ int s_cnt;
    __shared__ int s_selidx[K];
    __shared__ float s_seldist[K];

    // Issue all loads first; they stay in flight across the init barrier.
    f4 v[4];
    #pragma unroll
    for (int i = 0; i < 4; ++i)
        v[i] = __builtin_nontemporal_load(&row4[tid + i * BLOCK]);

    if (tid == 0) s_cnt = 0;
    __syncthreads();  // s_cnt init visible to all waves

    // ---- phase 1: filter + unordered LDS append ----
    #pragma unroll
    for (int i = 0; i < 4; ++i) {
        int bidx = (tid + i * BLOCK) * 4;
        #pragma unroll
        for (int c = 0; c < 4; ++c) {
            float d = v[i][c];
            if (d < CAND_T) {
                int pos = atomicAdd(&s_cnt, 1);
                if (pos < CAP)
                    s_keys[pos] =
                        ((unsigned long long)__float_as_uint(d) << 32) |
                        (unsigned int)(bidx + c);
            }
        }
    }
    __syncthreads();

    const int total = s_cnt;

    if (total >= K && total <= CAP) {
        // ---- rank select: rank = #keys strictly smaller (keys unique) ----
        for (int j = tid; j < total; j += BLOCK) {
            unsigned long long kj = s_keys[j];
            int rank = 0;
            for (int m2 = 0; m2 < total; ++m2)       // broadcast reads
                rank += (s_keys[m2] < kj) ? 1 : 0;
            if (rank < K) {
                s_selidx[rank] = (int)(kj & 0xFFFFFFFFull);
                s_seldist[rank] =
                    __uint_as_float((unsigned int)(kj >> 32));
            }
        }
    } else if (tid < 64) {
        // ---- exact wave-0 fallback (never taken on this input) ----
        const int lane = tid;
        unsigned long long last = 0ull;
        for (int r = 0; r < K; ++r) {
            unsigned long long best = ~0ull;
            for (int i = 0; i < 32; ++i) {
                int v4i = lane + i * 64;
                f4 w = __builtin_nontemporal_load(&row4[v4i]);
                int bidx = v4i * 4;
                #pragma unroll
                for (int c = 0; c < 4; ++c) {
                    float d = w[c];
                    float md = (d <= MAX_RADIUS) ? d
                                                 : __uint_as_float(0x7F800000u);
                    unsigned long long key =
                        ((unsigned long long)__float_as_uint(md) << 32) |
                        (unsigned int)(bidx + c);
                    if (((r == 0) || (key > last)) && key < best) best = key;
                }
            }
            #pragma unroll
            for (int off = 32; off > 0; off >>= 1) {
                unsigned long long other = __shfl_xor(best, off, 64);
                if (other < best) best = other;
            }
            if (lane == 0) {
                int idx = (int)(best & 0xFFFFFFFFull);
                s_selidx[r] = idx;
                s_seldist[r] = rowp[idx];  // original dm value
            }
            last = best;
        }
    }
    __syncthreads();  // selection visible to all waves

    // ---- outputs (non-temporal: never re-read) ----
    float* out_ei = out;
    float* out_ef = out + (size_t)N_ATOMS * K * 2;
    if (tid < 2 * K) {
        int r = tid >> 1, comp = tid & 1;
        __builtin_nontemporal_store(
            comp ? (float)s_selidx[r] : (float)row,
            &out_ei[((size_t)row * K + r) * 2 + comp]);
    }
    for (int t = tid; t < K * NBINS; t += BLOCK) {
        int r = t / NBINS, b = t - r * NBINS;
        float d = s_seldist[r];
        float z = (d - (float)b * (1.0f / 49.0f)) * 5.0f;
        __builtin_nontemporal_store(__expf(-0.5f * z * z),
                                    &out_ef[(size_t)row * K * NBINS + t]);
    }
}

extern "C" void kernel_launch(void* const* d_in, const int* in_sizes, int n_in,
                              void* d_out, int out_size, void* d_ws, size_t ws_size,
                              hipStream_t stream) {
    const float* dm = (const float*)d_in[0];
    float* out = (float*)d_out;
    edge_kernel<<<N_ATOMS, BLOCK, 0, stream>>>(dm, out);
}